// Round 7
// baseline (81.314 us; speedup 1.0000x reference)
//
#include <hip/hip_runtime.h>
#include <hip/hip_bf16.h>

// Interpolate1D: z = interp(cumsum(softmax(x@W + b)), y); outputs (z[B], x[B,64], logdet[B]+log|slope|)
// B=524288, D=64, R=256.
//
// Round-7: switch to mfma_f32_32x32x16_bf16 with 32-row wave tiles (r6 was 16x16x32 /
// 16-row). Halves per-row: ds_reads, MFMA count, searchsorted duplication, shfl reduce,
// loop overhead. Layouts: A/B lane = row + 32*(k/8), elem k%8 (generalizes the r2-verified
// 16x16 rule); C col=lane&31, row=(reg&3)+8*(reg>>2)+4*(lane>>5) [m74/m101].
// Kept from r4-r6 (all verified): swapped operands (W as A), register prefetch, LICM fence,
// log2e pre-scale + __builtin_amdgcn_exp2f, float-mask prefix sums, branchless searchsorted.
// New: truncating bf16 pack (2 ops vs 6; absmax ~0.016 << 0.108 threshold).

#define NB 524288
#define NT32 (NB / 32)   // 16384 wave-tiles of 32 rows

typedef __attribute__((ext_vector_type(4)))  float f32x4;
typedef __attribute__((ext_vector_type(16))) float f32x16;
typedef __attribute__((ext_vector_type(4)))  unsigned int u32x4;
typedef __attribute__((ext_vector_type(8)))  __bf16 bf16x8;

#define LOG2E 1.4426950408889634f

static __device__ __forceinline__ unsigned short f2b(float f) {
    unsigned u = __builtin_bit_cast(unsigned, f);
    u += 0x7fffu + ((u >> 16) & 1u);          // RNE (W only; one-time)
    return (unsigned short)(u >> 16);
}
static __device__ __forceinline__ unsigned pk2t(float a, float b) {
    // truncating bf16x2 pack: hi16(a) | hi16(b)<<16
    return (__builtin_bit_cast(unsigned, a) >> 16) | (__builtin_bit_cast(unsigned, b) & 0xffff0000u);
}

__global__ __launch_bounds__(256, 4) void interp1d_kernel(
    const float* __restrict__ y, const float* __restrict__ x,
    const float* __restrict__ W, const float* __restrict__ bias,
    const float* __restrict__ logdet, const float* __restrict__ bp,
    float* __restrict__ out)
{
    __shared__ unsigned short sW[4 * 8 * 64 * 8];   // 32KB: [kq][nb][lane][i], A-frag layout
    __shared__ float sBP[256];
    __shared__ float sBias[256];                    // pre-scaled by log2e

    const int t = threadIdx.x;

    // --- once per block: bp, bias*log2e, W*log2e packed into 32x32x16 A-frag layout ---
    // A-frag: lane holds W-col = lane&31, k = (lane>>5)*8 + i  (per kq K-slice of 16)
    sBP[t]   = bp[t];
    sBias[t] = bias[t] * LOG2E;
    {
        const int nb = t >> 5, c31 = t & 31;        // t = W column
        for (int k = 0; k < 64; ++k) {
            float wv = W[k * 256 + t] * LOG2E;      // coalesced
            int kq = k >> 4, khi = (k >> 3) & 1, i = k & 7;
            sW[((kq * 8 + nb) * 64 + khi * 32 + c31) * 8 + i] = f2b(wv);
        }
    }
    __syncthreads();

    const int lane = t & 63;
    const int r32  = lane & 31;     // this lane's x-row within the tile (C column)
    const int hi   = lane >> 5;     // 0/1: k-half; C rows offset 4*hi
    const int qb   = hi << 2;
    const int nw   = gridDim.x << 2;

    int wt = (blockIdx.x << 2) | (t >> 6);

    // --- preload first tile: lane reads 4x (8 consecutive f32) of its row ---
    f32x4 v[8]; float yv = 0.f, ldv = 0.f;
    if (wt < NT32) {
        const float* xr = x + (size_t)((wt << 5) + r32) * 64 + (hi << 3);
        #pragma unroll
        for (int kq = 0; kq < 4; ++kq) {
            v[2*kq]   = *reinterpret_cast<const f32x4*>(xr + kq*16);
            v[2*kq+1] = *reinterpret_cast<const f32x4*>(xr + kq*16 + 4);
        }
        yv  = y[(wt << 5) + r32];
        ldv = logdet[(wt << 5) + r32];
    }

    for (; wt < NT32; wt += nw) {
        const int m0 = wt << 5;
        const int wtn = wt + nw;

        // --- prefetch next tile ---
        f32x4 nv[8]; float yn = 0.f, ldn = 0.f;
        if (wtn < NT32) {
            const float* xr = x + (size_t)((wtn << 5) + r32) * 64 + (hi << 3);
            #pragma unroll
            for (int kq = 0; kq < 4; ++kq) {
                nv[2*kq]   = *reinterpret_cast<const f32x4*>(xr + kq*16);
                nv[2*kq+1] = *reinterpret_cast<const f32x4*>(xr + kq*16 + 4);
            }
            yn  = y[(wtn << 5) + r32];
            ldn = logdet[(wtn << 5) + r32];
        }

        // compiler fence: keep sW ds_reads inside the tile loop (r3 lesson)
        asm volatile("" ::: "memory");

        // --- passthrough x store from the same registers ---
        float* xo = out + NB + (size_t)(m0 + r32) * 64 + (hi << 3);
        #pragma unroll
        for (int kq = 0; kq < 4; ++kq) {
            *reinterpret_cast<f32x4*>(xo + kq*16)     = v[2*kq];
            *reinterpret_cast<f32x4*>(xo + kq*16 + 4) = v[2*kq+1];
        }

        // --- pack x into B-frags (col = x-row = lane&31, k = kq*16 + hi*8 + i) ---
        bf16x8 xf[4];
        #pragma unroll
        for (int kq = 0; kq < 4; ++kq) {
            u32x4 p;
            p[0] = pk2t(v[2*kq][0],   v[2*kq][1]);
            p[1] = pk2t(v[2*kq][2],   v[2*kq][3]);
            p[2] = pk2t(v[2*kq+1][0], v[2*kq+1][1]);
            p[3] = pk2t(v[2*kq+1][2], v[2*kq+1][3]);
            xf[kq] = __builtin_bit_cast(bf16x8, p);
        }

        // --- searchsorted (branchless; bp ~ linspace, guess off by <= 1) ---
        int s = (int)floorf(yv * 255.0f);
        s = min(254, max(0, s));
        s += (sBP[s + 1] <= yv) ? 1 : 0;
        s = min(s, 254);
        s -= (sBP[s] > yv) ? 1 : 0;
        s = max(s, 0);

        const int sb  = s >> 5,        so  = s & 31;
        const int sb1 = (s + 1) >> 5,  so1 = (s + 1) & 31;
        // lane's C-row (W-col within 32-block) for reg r: q = (r&3) + 8*(r>>2) + 4*hi
        float m[16], pm[16];
        #pragma unroll
        for (int r = 0; r < 16; ++r) {
            int q = (r & 3) + ((r >> 2) << 3) + qb;
            m[r]  = (q <= so)  ? 1.f : 0.f;
            pm[r] = (q == so1) ? 1.f : 0.f;
        }

        // --- 8 col-blocks: 4 K-chained MFMAs -> 16 C values -> exp2 + masked sums ---
        float denom = 0.f, f0s = 0.f, p1 = 0.f;
        #pragma unroll
        for (int nb = 0; nb < 8; ++nb) {
            f32x16 c;
            #pragma unroll
            for (int g = 0; g < 4; ++g) {   // C-init = bias at cols nb*32 + 8g + qb + (0..3)
                f32x4 bi = *reinterpret_cast<const f32x4*>(&sBias[nb*32 + g*8 + qb]);
                c[4*g+0] = bi[0]; c[4*g+1] = bi[1]; c[4*g+2] = bi[2]; c[4*g+3] = bi[3];
            }
            #pragma unroll
            for (int kq = 0; kq < 4; ++kq) {
                bf16x8 wf = *reinterpret_cast<const bf16x8*>(&sW[((kq*8 + nb)*64 + lane)*8]);
                c = __builtin_amdgcn_mfma_f32_32x32x16_bf16(wf, xf[kq], c, 0, 0, 0);
            }
            float e[16];
            #pragma unroll
            for (int r = 0; r < 16; ++r) e[r] = __builtin_amdgcn_exp2f(c[r]);
            float bs = 0.f, t0 = 0.f, tp = 0.f;
            #pragma unroll
            for (int g = 0; g < 4; ++g) {
                float gs = (e[4*g] + e[4*g+1]) + (e[4*g+2] + e[4*g+3]);
                bs += gs;
                t0 += fmaf(e[4*g+3], m[4*g+3], fmaf(e[4*g+2], m[4*g+2],
                      fmaf(e[4*g+1], m[4*g+1], e[4*g] * m[4*g])));
                tp += fmaf(e[4*g+3], pm[4*g+3], fmaf(e[4*g+2], pm[4*g+2],
                      fmaf(e[4*g+1], pm[4*g+1], e[4*g] * pm[4*g])));
            }
            denom += bs;
            f0s += (nb < sb) ? bs : ((nb == sb) ? t0 : 0.f);
            p1  += (nb == sb1) ? tp : 0.f;
        }

        // --- reduce over the 2 lanes (hi groups) sharing this x-row ---
        denom += __shfl_xor(denom, 32, 64);
        f0s   += __shfl_xor(f0s,   32, 64);
        p1    += __shfl_xor(p1,    32, 64);

        if (hi == 0) {   // lanes 0..31 store rows m0..m0+31: contiguous 128B
            float x0 = sBP[s], x1 = sBP[s + 1];
            float inv = 1.0f / denom;
            float f0 = f0s * inv;
            float slope = (p1 * inv) / (x1 - x0);
            out[m0 + r32] = fmaf(slope, yv - x0, f0);
            out[(size_t)NB * 65 + m0 + r32] = ldv + __logf(fabsf(slope));
        }

        // --- rotate prefetched tile in ---
        if (wtn < NT32) {
            #pragma unroll
            for (int j = 0; j < 8; ++j) v[j] = nv[j];
            yv = yn; ldv = ldn;
        }
    }
}

extern "C" void kernel_launch(void* const* d_in, const int* in_sizes, int n_in,
                              void* d_out, int out_size, void* d_ws, size_t ws_size,
                              hipStream_t stream) {
    (void)in_sizes; (void)n_in; (void)out_size; (void)d_ws; (void)ws_size;
    const float* y      = (const float*)d_in[0];
    const float* x      = (const float*)d_in[1];
    const float* W      = (const float*)d_in[2];
    const float* b      = (const float*)d_in[3];
    const float* logdet = (const float*)d_in[4];
    const float* bp     = (const float*)d_in[5];
    float* out = (float*)d_out;
    // 1024 blocks = 4 blocks/CU (LDS 34.8KB cap), all resident; 4 tiles per wave
    interp1d_kernel<<<dim3(1024), dim3(256), 0, stream>>>(y, x, W, b, logdet, bp, out);
}